// Round 4
// baseline (337.104 us; speedup 1.0000x reference)
//
#include <hip/hip_runtime.h>
#include <hip/hip_bf16.h>
#include <math.h>

#define B_SZ 256
#define F_SZ 2048
#define C_SZ 16384
#define P_SZ 8
#define N_SZ 32
#define NTILE 512   // C_SZ / 32 column tiles per row (one per wave-col-group)

typedef __bf16 bf16x8 __attribute__((ext_vector_type(8)));
typedef float f32x4 __attribute__((ext_vector_type(4)));
typedef unsigned short us8 __attribute__((ext_vector_type(8)));
typedef unsigned short us4 __attribute__((ext_vector_type(4)));

typedef __attribute__((address_space(3))) unsigned int lds_u32;
typedef __attribute__((address_space(1))) const unsigned int glb_u32;

__device__ __forceinline__ unsigned short f2bf(float x) {
    union { float f; unsigned int u; } v; v.f = x;
    unsigned int r = v.u + 0x7FFFu + ((v.u >> 16) & 1u);  // RTN-even
    return (unsigned short)(r >> 16);
}

// ---------------- kernel 1: row norms + bf16 cast of inputs ----------------
__global__ __launch_bounds__(256) void prep_kernel(const float* __restrict__ inputs,
                                                   unsigned short* __restrict__ Abf,
                                                   float* __restrict__ norms) {
    const int row = blockIdx.x;
    const int tid = threadIdx.x;
    const float* rp = inputs + (size_t)row * F_SZ + tid * 8;
    float4 v0 = *(const float4*)(rp);
    float4 v1 = *(const float4*)(rp + 4);
    us8 o;
    o[0]=f2bf(v0.x); o[1]=f2bf(v0.y); o[2]=f2bf(v0.z); o[3]=f2bf(v0.w);
    o[4]=f2bf(v1.x); o[5]=f2bf(v1.y); o[6]=f2bf(v1.z); o[7]=f2bf(v1.w);
    *(us8*)(Abf + (size_t)row * F_SZ + tid * 8) = o;
    float ss = v0.x*v0.x + v0.y*v0.y + v0.z*v0.z + v0.w*v0.w
             + v1.x*v1.x + v1.y*v1.y + v1.z*v1.z + v1.w*v1.w;
    __shared__ float red[256];
    red[tid] = ss; __syncthreads();
    for (int s = 128; s > 0; s >>= 1) { if (tid < s) red[tid] += red[tid+s]; __syncthreads(); }
    if (tid == 0) norms[row] = sqrtf(red[0]);
}

// ---------------- kernel 2: outputs = inputs @ V^T ----------------
// BM=256 (all rows -> V read ONCE), BN=64, BK=32, 1024 threads = 16 waves.
// Waves: wrow = wid&7 (32 rows each), wcol = wid>>3 (32 cols each); tile mi2 x ni2.
// A: global_load_lds chunk-major As[chunk(4)][row(256)] -> LDS slot index == tid.
// B: fp32 -> VGPR -> bf16 -> padded LDS (40 shorts/row).
#define BM 256
#define BN 64
#define BK 32
#define BPAD 40
#define KITERS (F_SZ / BK)

__global__ __launch_bounds__(1024) void gemm_kernel(const unsigned short* __restrict__ Abf,
                                                    const float* __restrict__ V,
                                                    float* __restrict__ Cout,
                                                    float* __restrict__ pmax,
                                                    float* __restrict__ psum) {
    __shared__ unsigned short As[2][4 * 256 * 8];   // 2 x 16 KB, slot = chunk*256+row
    __shared__ unsigned short Bs[2][BN * BPAD];     // 2 x 5 KB, padded

    const int tid = threadIdx.x;
    const int lane = tid & 63;
    const int wid = tid >> 6;
    const int wrow = wid & 7, wcol = wid >> 3;
    const int q = lane >> 4, l16 = lane & 15;
    const int bn0 = blockIdx.x * BN;

    f32x4 acc[2][2];
    #pragma unroll
    for (int i = 0; i < 2; i++)
        #pragma unroll
        for (int j = 0; j < 2; j++) acc[i][j] = (f32x4){0.f, 0.f, 0.f, 0.f};

    // ---- A staging: thread tid fetches chunk (tid>>8) of row (tid&255); slot = tid.
    const int arow = tid & 255, achk = tid >> 8;
    const unsigned short* AgBase = Abf + (size_t)arow * F_SZ + achk * 8;

    // ---- B staging: threads < 512; row = tid>>3 (0..63), seg = tid&7 (4 floats)
    const int brow = tid >> 3, bseg = tid & 7;
    const float* BgBase = V + (size_t)(bn0 + brow) * F_SZ + bseg * 4;
    unsigned short* Bsd0 = &Bs[0][brow * BPAD + bseg * 4];
    unsigned short* Bsd1 = &Bs[1][brow * BPAD + bseg * 4];

    float4 bv;

    auto issueA = [&](int buf, int k0) {
        __builtin_amdgcn_global_load_lds((glb_u32*)(AgBase + k0),
                                         (lds_u32*)&As[buf][(size_t)tid * 8], 16, 0, 0);
    };
    auto loadB = [&](int k0) {
        if (tid < 512) bv = *(const float4*)(BgBase + k0);
    };
    auto writeB = [&](unsigned short* dst) {
        if (tid < 512) {
            us4 w;
            w[0]=f2bf(bv.x); w[1]=f2bf(bv.y); w[2]=f2bf(bv.z); w[3]=f2bf(bv.w);
            *(us4*)dst = w;
        }
    };

    issueA(0, 0);
    loadB(0);
    writeB(Bsd0);
    __syncthreads();

    for (int it = 0; it < KITERS; ++it) {
        const int cur = it & 1;
        const bool more = (it + 1) < KITERS;
        if (more) {
            issueA(cur ^ 1, (it + 1) * BK);
            loadB((it + 1) * BK);
        }
        bf16x8 af[2], bfv[2];
        #pragma unroll
        for (int mi = 0; mi < 2; ++mi) {
            const int row = wrow * 32 + mi * 16 + l16;
            af[mi] = *(const bf16x8*)&As[cur][(size_t)(q * 256 + row) * 8];
        }
        #pragma unroll
        for (int ni = 0; ni < 2; ++ni) {
            const int col = wcol * 32 + ni * 16 + l16;
            bfv[ni] = *(const bf16x8*)&Bs[cur][col * BPAD + q * 8];
        }
        #pragma unroll
        for (int mi = 0; mi < 2; ++mi)
            #pragma unroll
            for (int ni = 0; ni < 2; ++ni)
                acc[mi][ni] = __builtin_amdgcn_mfma_f32_16x16x32_bf16(af[mi], bfv[ni], acc[mi][ni], 0, 0, 0);
        if (more) writeB(cur ? Bsd0 : Bsd1);
        __syncthreads();
    }

    // epilogue: D row=(lane>>4)*4+reg, col=lane&15  [verified m89/m91]
    #pragma unroll
    for (int mi = 0; mi < 2; ++mi) {
        const int r0 = wrow * 32 + mi * 16 + q * 4;
        #pragma unroll
        for (int ni = 0; ni < 2; ++ni) {
            const int c0 = bn0 + wcol * 32 + ni * 16 + l16;
            #pragma unroll
            for (int r = 0; r < 4; ++r)
                Cout[(size_t)(r0 + r) * C_SZ + c0] = acc[mi][ni][r];
        }
    }

    // fused partial softmax over this wave's 32 columns per row
    const int tileIdx = blockIdx.x * 2 + wcol;
    #pragma unroll
    for (int mi = 0; mi < 2; ++mi) {
        #pragma unroll
        for (int r = 0; r < 4; ++r) {
            float mloc = fmaxf(acc[mi][0][r], acc[mi][1][r]);
            #pragma unroll
            for (int off = 1; off < 16; off <<= 1)
                mloc = fmaxf(mloc, __shfl_xor(mloc, off, 64));
            float sloc = __expf(acc[mi][0][r] - mloc) + __expf(acc[mi][1][r] - mloc);
            #pragma unroll
            for (int off = 1; off < 16; off <<= 1)
                sloc += __shfl_xor(sloc, off, 64);
            if (l16 == 0) {
                const int grow = wrow * 32 + mi * 16 + q * 4 + r;
                pmax[grow * NTILE + tileIdx] = mloc;
                psum[grow * NTILE + tileIdx] = sloc;
            }
        }
    }
}

// ---------------- kernel 3: merge softmax partials -> bu_part ----------------
__global__ __launch_bounds__(256) void softmax_combine_kernel(
    const float* __restrict__ pmax, const float* __restrict__ psum,
    const float* __restrict__ outputs, const int* __restrict__ targets,
    float* __restrict__ bu_part)
{
    const int row = blockIdx.x;
    const int tid = threadIdx.x;
    __shared__ float rm[256], rs[256];
    // merge tid and tid+256 first (NTILE=512)
    float m1 = pmax[row * NTILE + tid],       s1 = psum[row * NTILE + tid];
    float m2 = pmax[row * NTILE + tid + 256], s2 = psum[row * NTILE + tid + 256];
    float nm = fmaxf(m1, m2);
    rm[tid] = nm;
    rs[tid] = s1 * __expf(m1 - nm) + s2 * __expf(m2 - nm);
    __syncthreads();
    for (int s = 128; s > 0; s >>= 1) {
        if (tid < s) {
            float a = rm[tid], sa = rs[tid];
            float b = rm[tid + s], sb = rs[tid + s];
            float nn = fmaxf(a, b);
            rs[tid] = sa * __expf(a - nn) + sb * __expf(b - nn);
            rm[tid] = nn;
        }
        __syncthreads();
    }
    if (tid == 0) {
        float logZ = rm[0] + logf(rs[0]);
        bu_part[row] = -(outputs[(size_t)row * C_SZ + targets[row]] - logZ);
    }
}

// ---------------- kernel 4: pair matching + sims + hard-pair sums ----------------
__global__ __launch_bounds__(256) void pairs_kernel(
    const float* __restrict__ inputs, const int* __restrict__ targets,
    const int* __restrict__ ppairs, const int* __restrict__ npairs,
    const int* __restrict__ indexs, const int* __restrict__ cluster,
    const float* __restrict__ outputs, const float* __restrict__ norms,
    float* __restrict__ hp_part, float* __restrict__ hn_part,
    int* __restrict__ flag_part)
{
    const int i = blockIdx.x;
    const int tid = threadIdx.x;
    __shared__ int idxbuf[B_SZ];
    __shared__ int pj[P_SZ];
    __shared__ int nj[N_SZ];
    __shared__ float simp[P_SZ];
    __shared__ float simn[N_SZ];
    __shared__ float tnv[N_SZ];
    __shared__ float s_tp;

    idxbuf[tid] = indexs[tid];
    __syncthreads();

    const float* row = outputs + (size_t)i * C_SZ;
    const float ni_norm = norms[i];

    // pair matching (indexs is a permutation -> at most one match; argmax = first)
    if (tid < P_SZ) {
        int pp = ppairs[i * P_SZ + tid];
        int f = -1;
        if (pp >= 0) for (int j = 0; j < B_SZ; j++) if (idxbuf[j] == pp) { f = j; break; }
        pj[tid] = f;
    } else if (tid < P_SZ + N_SZ) {
        int t = tid - P_SZ;
        int np = npairs[i * N_SZ + t];
        int f = -1;
        if (np >= 0) for (int j = 0; j < B_SZ; j++) if (idxbuf[j] == np) { f = j; break; }
        nj[t] = f;
        int cid = cluster[np < 0 ? 0 : np];           // jnp.clip(npairs, 0)
        tnv[t] = row[cid] / ni_norm;                  // tsims[i, ncid] = outputs/norm
    }
    if (tid == P_SZ + N_SZ) s_tp = row[targets[i]] / ni_norm;
    __syncthreads();

    // in-batch sims (fp32, exact semantics incl. self-match ~1.0): one pair per wave round-robin
    const int lane = tid & 63, wv = tid >> 6;
    for (int qq = wv; qq < P_SZ + N_SZ; qq += 4) {
        int j = (qq < P_SZ) ? pj[qq] : nj[qq - P_SZ];
        float s = 0.f;
        if (j >= 0) {
            const float* xi = inputs + (size_t)i * F_SZ;
            const float* xj = inputs + (size_t)j * F_SZ;
            float d = 0.f;
            for (int k = lane; k < F_SZ; k += 64) d += xi[k] * xj[k];
            for (int off = 32; off > 0; off >>= 1) d += __shfl_down(d, off);
            s = d / (ni_norm * norms[j]);
        }
        if (lane == 0) { if (qq < P_SZ) simp[qq] = s; else simn[qq - P_SZ] = s; }
    }
    __syncthreads();

    if (tid == 0) {
        float psims[P_SZ + 1]; bool pmask[P_SZ + 1];
        for (int p = 0; p < P_SZ; p++) {
            int pp = ppairs[i * P_SZ + p];
            pmask[p] = (pj[p] >= 0) && (pp >= 0);
            psims[p] = simp[p];
        }
        psims[P_SZ] = s_tp; pmask[P_SZ] = (s_tp != 0.0f);

        float nsims[2 * N_SZ]; bool nmask[2 * N_SZ];
        for (int t = 0; t < N_SZ; t++) {
            int np = npairs[i * N_SZ + t];
            nmask[t] = (nj[t] >= 0) && (np >= 0);
            nsims[t] = simn[t];
            nsims[N_SZ + t] = tnv[t];
            nmask[N_SZ + t] = (np >= 0) && (tnv[t] != 0.0f);
        }
        bool anyp = false, anyn = false;
        float maxn = -INFINITY, minp = INFINITY;
        for (int t = 0; t < 2 * N_SZ; t++) if (nmask[t]) { anyn = true; maxn = fmaxf(maxn, nsims[t]); }
        for (int p = 0; p < P_SZ + 1; p++) if (pmask[p]) { anyp = true; minp = fminf(minp, psims[p]); }
        float p_thrd = (anyn ? maxn : -3.0f) + 0.1f;
        float n_thrd = (anyp ? minp : 3.0f) - 0.1f;
        float hps = 0.f, hns = 0.f; int fl = 0;
        for (int p = 0; p < P_SZ + 1; p++)
            if (pmask[p] && psims[p] < p_thrd) { fl |= 1; hps += expf(-2.0f * (psims[p] - 0.5f)); }
        for (int t = 0; t < 2 * N_SZ; t++)
            if (nmask[t] && nsims[t] > n_thrd && nsims[t] < 0.999999f) { fl |= 2; hns += expf(50.0f * (nsims[t] - 0.5f)); }
        hp_part[i] = hps; hn_part[i] = hns; flag_part[i] = fl;
    }
}

// ---------------- kernel 5: final scalar reduce ----------------
__global__ __launch_bounds__(256) void finalize_kernel(
    const float* __restrict__ bu_part, const float* __restrict__ hp_part,
    const float* __restrict__ hn_part, const int* __restrict__ flag_part,
    float* __restrict__ d_out)
{
    __shared__ float r1[256], r2[256], r3[256];
    __shared__ int rf[256];
    const int tid = threadIdx.x;
    r1[tid] = bu_part[tid]; r2[tid] = hp_part[tid]; r3[tid] = hn_part[tid]; rf[tid] = flag_part[tid];
    __syncthreads();
    for (int s = 128; s > 0; s >>= 1) {
        if (tid < s) { r1[tid] += r1[tid+s]; r2[tid] += r2[tid+s]; r3[tid] += r3[tid+s]; rf[tid] |= rf[tid+s]; }
        __syncthreads();
    }
    if (tid == 0) {
        float bu = r1[0] / (float)B_SZ;
        float hp_loss = (rf[0] & 1) ? 0.5f * log1pf(r2[0]) : 0.0f;
        float hn_loss = (rf[0] & 2) ? (1.0f / 50.0f) * log1pf(r3[0]) : 0.0f;
        d_out[0] = 1.0f * bu + 10.0f * (hp_loss + hn_loss);   // W_BU=1, W_H=10
    }
}

extern "C" void kernel_launch(void* const* d_in, const int* in_sizes, int n_in,
                              void* d_out, int out_size, void* d_ws, size_t ws_size,
                              hipStream_t stream) {
    const float* inputs  = (const float*)d_in[0];
    const int*   targets = (const int*)d_in[1];
    const int*   ppairs  = (const int*)d_in[2];
    const int*   npairs  = (const int*)d_in[3];
    const int*   indexs  = (const int*)d_in[4];
    const int*   cluster = (const int*)d_in[5];
    const float* V       = (const float*)d_in[6];
    float* out = (float*)d_out;           // [0] = loss, [1..] = outputs row-major [B][C]

    char* ws = (char*)d_ws;
    unsigned short* Abf = (unsigned short*)ws;                       // 1 MB
    float* norms   = (float*)(ws + (size_t)B_SZ * F_SZ * 2);
    float* bu_part = norms + B_SZ;
    float* hp_part = bu_part + B_SZ;
    float* hn_part = hp_part + B_SZ;
    int*   flag_part = (int*)(hn_part + B_SZ);
    float* pmax = (float*)(flag_part + B_SZ);                        // 512 KB
    float* psum = pmax + (size_t)B_SZ * NTILE;                       // 512 KB

    prep_kernel<<<B_SZ, 256, 0, stream>>>(inputs, Abf, norms);
    gemm_kernel<<<dim3(C_SZ / BN, 1), 1024, 0, stream>>>(Abf, V, out + 1, pmax, psum);
    softmax_combine_kernel<<<B_SZ, 256, 0, stream>>>(pmax, psum, out + 1, targets, bu_part);
    pairs_kernel<<<B_SZ, 256, 0, stream>>>(inputs, targets, ppairs, npairs, indexs,
                                           cluster, out + 1, norms,
                                           hp_part, hn_part, flag_part);
    finalize_kernel<<<1, 256, 0, stream>>>(bu_part, hp_part, hn_part, flag_part, out);
}